// Round 1
// baseline (346.697 us; speedup 1.0000x reference)
//
#include <hip/hip_runtime.h>

#define B_N   262144
#define PMIN_F 0.001f
#define LOG2E 1.44269504088896340736f
#define LN2   0.69314718055994530942f

typedef _Float16 half4v __attribute__((ext_vector_type(4)));
typedef _Float16 half8  __attribute__((ext_vector_type(8)));
typedef float    floatx4 __attribute__((ext_vector_type(4)));

__device__ __forceinline__ float fexp2(float x) { return __builtin_amdgcn_exp2f(x); }
__device__ __forceinline__ float flog2(float x) { return __builtin_amdgcn_logf(x); }
__device__ __forceinline__ float frcp (float x) { return __builtin_amdgcn_rcpf(x); }

// ---------------------------------------------------------------------------
// Prep: weights fp32 -> f16 in MFMA B-fragment order (unchanged).
//   r in [0,8)   : mm1 W1 16x128, K padded to 32; k==16 row carries b1
//   r in [8,40)  : mm2 Wh 128x128
//   r in [40,104): mm3 Wo 128x248 column-remapped to 256 (31->32 pad per d)
// ---------------------------------------------------------------------------
__global__ __launch_bounds__(64) void prep_kernel(
    const float* __restrict__ W1s, const float* __restrict__ b1s,
    const float* __restrict__ Whs, const float* __restrict__ Wos,
    _Float16* __restrict__ ws)
{
    const int bid   = blockIdx.x;          // 0..415
    const int layer = bid / 104;
    const int r     = bid % 104;
    const int lane  = threadIdx.x;
    const int kg    = lane >> 4;
    const int c     = lane & 15;

    half8 v;
    if (r < 8) {
        const int nt = r, n = nt * 16 + c;
        const float* W1 = W1s + layer * 16 * 128;
        const float* b1 = b1s + layer * 128;
        #pragma unroll
        for (int j = 0; j < 8; ++j) {
            const int k = kg * 8 + j;
            v[j] = (k < 16) ? (_Float16)W1[k * 128 + n]
                 : (k == 16) ? (_Float16)b1[n] : (_Float16)0.f;
        }
    } else if (r < 40) {
        const int f = r - 8, nt = f >> 2, ks = f & 3, n = nt * 16 + c;
        const float* Wh = Whs + layer * 128 * 128;
        #pragma unroll
        for (int j = 0; j < 8; ++j) {
            const int k = ks * 32 + kg * 8 + j;
            v[j] = (_Float16)Wh[k * 128 + n];
        }
    } else {
        const int f = r - 40, nt = f >> 2, ks = f & 3, n = nt * 16 + c;
        const int dd = n >> 5, cc = n & 31;
        const float* Wo = Wos + layer * 128 * 248;
        #pragma unroll
        for (int j = 0; j < 8; ++j) {
            const int k = ks * 32 + kg * 8 + j;
            v[j] = (cc < 31) ? (_Float16)Wo[k * 248 + dd * 31 + cc] : (_Float16)0.f;
        }
    }
    *(half8*)(ws + (size_t)bid * 512 + lane * 8) = v;
}

// ---------------------------------------------------------------------------
// Spline for one item (verbatim math from the verified 2-tile kernel).
// Rf points at this tile's f32 theta overlay; base = row*68 + dl*32.
// ---------------------------------------------------------------------------
__device__ __forceinline__ void spline_eval(const float* __restrict__ Rf, const int base,
                                            const float x2, float& yout, float& ljout)
{
    const float4 v0 = *(const float4*)&Rf[base];
    const float4 v1 = *(const float4*)&Rf[base + 4];
    const float4 v2 = *(const float4*)&Rf[base + 8];
    const float4 v3 = *(const float4*)&Rf[base + 12];
    const float4 v4 = *(const float4*)&Rf[base + 16];

    float tw[10] = {v0.x, v0.y, v0.z, v0.w, v1.x, v1.y, v1.z, v1.w, v2.x, v2.y};
    float m1 = tw[0];
    #pragma unroll
    for (int i = 1; i < 10; ++i) m1 = fmaxf(m1, tw[i]);
    float se = 0.f;
    #pragma unroll
    for (int i = 0; i < 10; ++i) { tw[i] = fexp2((tw[i] - m1) * LOG2E); se += tw[i]; }
    const float inv198 = 1.98f * frcp(se);   // 2*(1-PMIN*K)/sum

    int cnt = 0;
    {
        float run = -1.f;
        cnt += (run < x2) ? 1 : 0;
        #pragma unroll
        for (int i = 0; i < 10; ++i) {
            run = run + fmaf(tw[i], inv198, 0.002f);
            cnt += (run < x2) ? 1 : 0;
        }
    }
    const int bidx = cnt - 1;
    const bool inb = (bidx >= 0) && (bidx < 10);
    const int ci = bidx < 0 ? 0 : (bidx > 9 ? 9 : bidx);

    float xlo = -1.f, xhi = 0.f, rx;
    {
        float run = -1.f;
        #pragma unroll
        for (int i = 0; i < 10; ++i) {
            const bool pick = (i == ci);
            xlo = pick ? run : xlo;
            run = run + fmaf(tw[i], inv198, 0.002f);
            xhi = pick ? run : xhi;
        }
        rx = run;
    }

    float hh[10] = {v2.z, v2.w, v3.x, v3.y, v3.z, v3.w, v4.x, v4.y, v4.z, v4.w};
    float hm = hh[0];
    #pragma unroll
    for (int i = 1; i < 10; ++i) hm = fmaxf(hm, hh[i]);
    float seh = 0.f;
    #pragma unroll
    for (int i = 0; i < 10; ++i) { hh[i] = fexp2((hh[i] - hm) * LOG2E); seh += hh[i]; }
    const float invh = 1.98f * frcp(seh);
    float ylo = -1.f, yhi = 0.f, ry;
    {
        float run = -1.f;
        #pragma unroll
        for (int i = 0; i < 10; ++i) {
            const bool pick = (i == ci);
            ylo = pick ? run : ylo;
            run = run + fmaf(hh[i], invh, 0.002f);
            yhi = pick ? run : yhi;
        }
        ry = run;
    }

    const float xw = xhi - xlo, yw = yhi - ylo;

    const float u1 = Rf[base + 20 + ci];
    const float u2 = Rf[base + 21 + ci];
    const float t1 = u1 * LOG2E;
    const float t2s = u2 * LOG2E;
    const float dd1 = PMIN_F + 0.999f * ((t1  > 15.f) ? t1  : flog2(1.f + fexp2(t1)));
    const float dd2 = PMIN_F + 0.999f * ((t2s > 15.f) ? t2s : flog2(1.f + fexp2(t2s)));

    const float xs  = inb ? x2 : (xlo + 0.5f * xw);
    const float rxw = frcp(xw);
    const float s   = yw * rxw;
    const float eta = (xs - xlo) * rxw;
    const float rev = 1.f - eta;
    const float er  = eta * rev;
    const float dn  = s + (dd1 + dd2 - 2.f * s) * er;
    const float yrq = ylo + yw * (s * eta * eta + dd1 * er) * frcp(dn);
    const float jn  = s * s * (dd2 * eta * eta + 2.f * s * er + dd1 * rev * rev);
    const float ljx = LN2 * (flog2(jn) - 2.f * flog2(dn));
    const float ylin = (ry + 1.f) * frcp(rx + 1.f) * (x2 + 1.f) - 1.f;

    yout  = inb ? yrq : ylin;
    ljout = inb ? ljx : 0.f;
}

// ---------------------------------------------------------------------------
// Main: one wave = 64 rows (4 tiles).  Rationale vs the 2-tile version:
// each wave streams the full 416 KB packed-weight set from L2 regardless of
// row count, and at 32 rows/wave that was 3.4 GB of L2 traffic (15 TB/s,
// 44% of ceiling) with queued-latency stalls dominating wave lifetime.
// 4 tiles halves weight traffic and doubles per-load MFMA amortization and
// intra-wave ILP (4 independent accumulator chains, 2 splines/lane/quarter).
// Layouts, strides (h f16 stride 132 / theta f32 stride 68), barrier/fence
// placement and spline math are byte-identical to the verified 2-tile kernel.
// LDS: R[4][2176] (17408 B) + xls[4][256] (4096 B) = 21504 B -> 7 WG/CU.
// __launch_bounds__(64,2) caps arch VGPR at 256 (no spill; LDS binds first).
// ---------------------------------------------------------------------------
__global__ __launch_bounds__(64, 2) void flow_mfma(
    const float* __restrict__ x_in,
    const float* __restrict__ c_in,
    const float* __restrict__ bhs,
    const float* __restrict__ bos,
    const int*   __restrict__ perms,
    const _Float16* __restrict__ wsW,
    float* __restrict__ out)
{
    __shared__ __align__(16) float    xls[4][256];   // [tile][16 rows][16]
    __shared__ __align__(16) _Float16 R[4][2176];    // h(f16,132) / theta(f32,68)

    const int lane = threadIdx.x;
    const int q    = lane >> 4;
    const int m    = lane & 15;
    const long long row0 = (long long)blockIdx.x * 64;

    {
        const float4* xp = (const float4*)(x_in + row0 * 16);
        #pragma unroll
        for (int t = 0; t < 4; ++t)
            *(float4*)&xls[t][lane * 4] = xp[lane + t * 64];
    }

    // layer-invariant part of the mm1 A-fragment (c data / bias-one)
    half8 a1c[4];
    #pragma unroll
    for (int t = 0; t < 4; ++t) {
        #pragma unroll
        for (int j = 0; j < 8; ++j) a1c[t][j] = (_Float16)0.f;
        if (q == 1) {
            const float4* cp = (const float4*)(c_in + (row0 + t * 16 + m) * 8);
            const float4 c0 = cp[0], c1 = cp[1];
            a1c[t][0] = (_Float16)c0.x; a1c[t][1] = (_Float16)c0.y;
            a1c[t][2] = (_Float16)c0.z; a1c[t][3] = (_Float16)c0.w;
            a1c[t][4] = (_Float16)c1.x; a1c[t][5] = (_Float16)c1.y;
            a1c[t][6] = (_Float16)c1.z; a1c[t][7] = (_Float16)c1.w;
        } else if (q == 2) {
            a1c[t][0] = (_Float16)1.f;   // k=16 -> bias row
        }
    }

    // spline item mapping (fixed per lane): tile pair {sp_ta, sp_ta+2}, row, d-parity
    const int sp_ta  = lane >> 5;
    const int sp_row = (lane & 31) >> 1;
    const int sp_dl  = lane & 1;

    float ljA = 0.f, ljB = 0.f;

    for (int l = 0; l < 4; ++l) {
        const _Float16* wsl = wsW + (size_t)l * 104 * 512;
        const float* bh = bhs + l * 128;
        const float* bo = bos + l * 248;

        // ================= mm1: [x1,c,1] @ [W1;b1] -> h1 (f16) =============
        half8 a1[4];
        #pragma unroll
        for (int t = 0; t < 4; ++t) {
            a1[t] = a1c[t];
            if (q == 0) {
                const float4 lo = *(const float4*)&xls[t][m * 16];
                const float4 hi = *(const float4*)&xls[t][m * 16 + 4];
                a1[t][0] = (_Float16)lo.x; a1[t][1] = (_Float16)lo.y;
                a1[t][2] = (_Float16)lo.z; a1[t][3] = (_Float16)lo.w;
                a1[t][4] = (_Float16)hi.x; a1[t][5] = (_Float16)hi.y;
                a1[t][6] = (_Float16)hi.z; a1[t][7] = (_Float16)hi.w;
            }
        }
        #pragma unroll
        for (int g = 0; g < 2; ++g) {
            const floatx4 z = {0.f, 0.f, 0.f, 0.f};
            floatx4 acc[4][4];
            #pragma unroll
            for (int nt = 0; nt < 4; ++nt) {
                const half8 b = *(const half8*)(wsl + (g * 4 + nt) * 512 + lane * 8);
                #pragma unroll
                for (int t = 0; t < 4; ++t)
                    acc[t][nt] = __builtin_amdgcn_mfma_f32_16x16x32_f16(a1[t], b, z, 0, 0, 0);
            }
            #pragma unroll
            for (int nt = 0; nt < 4; ++nt)
                #pragma unroll
                for (int reg = 0; reg < 4; ++reg)
                    #pragma unroll
                    for (int t = 0; t < 4; ++t)
                        R[t][(q * 4 + reg) * 132 + (g * 4 + nt) * 16 + m] =
                            (_Float16)fmaxf(acc[t][nt][reg], 0.f);
        }

        // ===== mm2: pull h1 A-frags (in-order LDS, no barrier needed) ======
        half8 a2[4][4];
        #pragma unroll
        for (int t = 0; t < 4; ++t)
            #pragma unroll
            for (int ks = 0; ks < 4; ++ks) {
                const half4v lo = *(const half4v*)&R[t][m * 132 + ks * 32 + q * 8];
                const half4v hi = *(const half4v*)&R[t][m * 132 + ks * 32 + q * 8 + 4];
                a2[t][ks] = __builtin_shufflevector(lo, hi, 0, 1, 2, 3, 4, 5, 6, 7);
            }
        #pragma unroll
        for (int g = 0; g < 2; ++g) {
            floatx4 acc[4][4];
            #pragma unroll
            for (int nt = 0; nt < 4; ++nt) {
                const float bb = bh[(g * 4 + nt) * 16 + m];
                #pragma unroll
                for (int t = 0; t < 4; ++t) {
                    acc[t][nt][0] = bb; acc[t][nt][1] = bb;
                    acc[t][nt][2] = bb; acc[t][nt][3] = bb;
                }
            }
            #pragma unroll
            for (int ks = 0; ks < 4; ++ks)
                #pragma unroll
                for (int nt = 0; nt < 4; ++nt) {
                    const half8 b = *(const half8*)(wsl + (8 + (g * 4 + nt) * 4 + ks) * 512 + lane * 8);
                    #pragma unroll
                    for (int t = 0; t < 4; ++t)
                        acc[t][nt] = __builtin_amdgcn_mfma_f32_16x16x32_f16(a2[t][ks], b, acc[t][nt], 0, 0, 0);
                }
            #pragma unroll
            for (int nt = 0; nt < 4; ++nt)
                #pragma unroll
                for (int reg = 0; reg < 4; ++reg)
                    #pragma unroll
                    for (int t = 0; t < 4; ++t)
                        R[t][(q * 4 + reg) * 132 + (g * 4 + nt) * 16 + m] =
                            (_Float16)fmaxf(acc[t][nt][reg], 0.f);
        }

        // ===== mm3: pull h2 A-frags to regs (before theta overwrites h) ====
        half8 a3[4][4];
        #pragma unroll
        for (int t = 0; t < 4; ++t)
            #pragma unroll
            for (int ks = 0; ks < 4; ++ks) {
                const half4v lo = *(const half4v*)&R[t][m * 132 + ks * 32 + q * 8];
                const half4v hi = *(const half4v*)&R[t][m * 132 + ks * 32 + q * 8 + 4];
                a3[t][ks] = __builtin_shufflevector(lo, hi, 0, 1, 2, 3, 4, 5, 6, 7);
            }
        __syncthreads();   // FENCE: f16 h-reads above vs f32 theta-writes below

        #pragma unroll
        for (int qd = 0; qd < 4; ++qd) {
            // ---- mm3 quarter: cols [qd*64, qd*64+64) = d in {qd*2, qd*2+1}
            {
                floatx4 acc[4][4];
                #pragma unroll
                for (int j = 0; j < 4; ++j) {
                    const int n = qd * 64 + j * 16 + m;
                    const int cc = n & 31;
                    const float bb = (cc < 31) ? bo[(n >> 5) * 31 + cc] : 0.f;
                    #pragma unroll
                    for (int t = 0; t < 4; ++t) {
                        acc[t][j][0] = bb; acc[t][j][1] = bb;
                        acc[t][j][2] = bb; acc[t][j][3] = bb;
                    }
                }
                #pragma unroll
                for (int ks = 0; ks < 4; ++ks)
                    #pragma unroll
                    for (int j = 0; j < 4; ++j) {
                        const int nt = qd * 4 + j;
                        const half8 b = *(const half8*)(wsl + (40 + nt * 4 + ks) * 512 + lane * 8);
                        #pragma unroll
                        for (int t = 0; t < 4; ++t)
                            acc[t][j] = __builtin_amdgcn_mfma_f32_16x16x32_f16(a3[t][ks], b, acc[t][j], 0, 0, 0);
                    }
                // store theta as f32: addr = row*68 + (j>>1)*32 + ((j&1)*16+m)
                #pragma unroll
                for (int j = 0; j < 4; ++j) {
                    const int off = (j >> 1) * 32 + (j & 1) * 16 + m;
                    #pragma unroll
                    for (int reg = 0; reg < 4; ++reg)
                        #pragma unroll
                        for (int t = 0; t < 4; ++t)
                            ((float*)&R[t][0])[(q * 4 + reg) * 68 + off] = acc[t][j][reg];
                }
            }

            // ---- spline quarter: 128 items, 2/lane: tiles sp_ta and sp_ta+2
            {
                const int d    = qd * 2 + sp_dl;
                const int base = sp_row * 68 + sp_dl * 32;
                const int xi   = sp_row * 16 + 8 + d;

                float yA, lA, yB, lB;
                spline_eval((const float*)&R[sp_ta][0],     base, xls[sp_ta][xi],     yA, lA);
                spline_eval((const float*)&R[sp_ta + 2][0], base, xls[sp_ta + 2][xi], yB, lB);

                xls[sp_ta][xi]     = yA;
                xls[sp_ta + 2][xi] = yB;
                ljA += lA;
                ljB += lB;
            }
        }

        // ================= permutation (in-order LDS, same-type) ===========
        {
            const int4 pv = ((const int4*)(perms + l * 16))[lane & 3];
            const int mm = lane >> 2;
            #pragma unroll
            for (int t = 0; t < 4; ++t) {
                const float a0  = xls[t][mm * 16 + pv.x];
                const float a1v = xls[t][mm * 16 + pv.y];
                const float a2v = xls[t][mm * 16 + pv.z];
                const float a3v = xls[t][mm * 16 + pv.w];
                *(float4*)&xls[t][lane * 4] = make_float4(a0, a1v, a2v, a3v);
            }
        }
        __syncthreads();   // FENCE: f32 theta-reads this layer vs f16 h-writes next
    }

    // ---- outputs: x [B,16] then ljd [B]
    #pragma unroll
    for (int t = 0; t < 4; ++t) {
        const float4 vo = *(const float4*)&xls[t][lane * 4];
        ((float4*)(out + (row0 + t * 16) * 16))[lane] = vo;
    }
    {
        const float sA = ljA + __shfl_xor(ljA, 1);
        const float sB = ljB + __shfl_xor(ljB, 1);
        if ((lane & 1) == 0) {
            out[(size_t)B_N * 16 + row0 + sp_ta * 16 + sp_row]       = sA;
            out[(size_t)B_N * 16 + row0 + (sp_ta + 2) * 16 + sp_row] = sB;
        }
    }
}

extern "C" void kernel_launch(void* const* d_in, const int* in_sizes, int n_in,
                              void* d_out, int out_size, void* d_ws, size_t ws_size,
                              hipStream_t stream) {
    const float* x     = (const float*)d_in[0];
    const float* c     = (const float*)d_in[1];
    const float* W1s   = (const float*)d_in[2];
    const float* b1s   = (const float*)d_in[3];
    const float* Whs   = (const float*)d_in[4];
    const float* bhs   = (const float*)d_in[5];
    const float* Wos   = (const float*)d_in[6];
    const float* bos   = (const float*)d_in[7];
    const int*   perms = (const int*)d_in[8];
    float* out = (float*)d_out;
    _Float16* ws = (_Float16*)d_ws;

    prep_kernel<<<dim3(416), dim3(64), 0, stream>>>(W1s, b1s, Whs, Wos, ws);
    flow_mfma<<<dim3(B_N / 64), dim3(64), 0, stream>>>(
        x, c, bhs, bos, perms, ws, out);
}

// Round 2
// 262.041 us; speedup vs baseline: 1.3231x; 1.3231x over previous
//
#include <hip/hip_runtime.h>

#define B_N   262144
#define PMIN_F 0.001f
#define LOG2E 1.44269504088896340736f
#define LN2   0.69314718055994530942f

typedef _Float16 half4v __attribute__((ext_vector_type(4)));
typedef _Float16 half8  __attribute__((ext_vector_type(8)));
typedef float    floatx4 __attribute__((ext_vector_type(4)));

__device__ __forceinline__ float fexp2(float x) { return __builtin_amdgcn_exp2f(x); }
__device__ __forceinline__ float flog2(float x) { return __builtin_amdgcn_logf(x); }
__device__ __forceinline__ float frcp (float x) { return __builtin_amdgcn_rcpf(x); }

// ---------------------------------------------------------------------------
// Prep: weights fp32 -> f16 in MFMA B-fragment order (unchanged).
//   r in [0,8)   : mm1 W1 16x128, K padded to 32; k==16 row carries b1
//   r in [8,40)  : mm2 Wh 128x128
//   r in [40,104): mm3 Wo 128x248 column-remapped to 256 (31->32 pad per d)
// ---------------------------------------------------------------------------
__global__ __launch_bounds__(64) void prep_kernel(
    const float* __restrict__ W1s, const float* __restrict__ b1s,
    const float* __restrict__ Whs, const float* __restrict__ Wos,
    _Float16* __restrict__ ws)
{
    const int bid   = blockIdx.x;          // 0..415
    const int layer = bid / 104;
    const int r     = bid % 104;
    const int lane  = threadIdx.x;
    const int kg    = lane >> 4;
    const int c     = lane & 15;

    half8 v;
    if (r < 8) {
        const int nt = r, n = nt * 16 + c;
        const float* W1 = W1s + layer * 16 * 128;
        const float* b1 = b1s + layer * 128;
        #pragma unroll
        for (int j = 0; j < 8; ++j) {
            const int k = kg * 8 + j;
            v[j] = (k < 16) ? (_Float16)W1[k * 128 + n]
                 : (k == 16) ? (_Float16)b1[n] : (_Float16)0.f;
        }
    } else if (r < 40) {
        const int f = r - 8, nt = f >> 2, ks = f & 3, n = nt * 16 + c;
        const float* Wh = Whs + layer * 128 * 128;
        #pragma unroll
        for (int j = 0; j < 8; ++j) {
            const int k = ks * 32 + kg * 8 + j;
            v[j] = (_Float16)Wh[k * 128 + n];
        }
    } else {
        const int f = r - 40, nt = f >> 2, ks = f & 3, n = nt * 16 + c;
        const int dd = n >> 5, cc = n & 31;
        const float* Wo = Wos + layer * 128 * 248;
        #pragma unroll
        for (int j = 0; j < 8; ++j) {
            const int k = ks * 32 + kg * 8 + j;
            v[j] = (cc < 31) ? (_Float16)Wo[k * 248 + dd * 31 + cc] : (_Float16)0.f;
        }
    }
    *(half8*)(ws + (size_t)bid * 512 + lane * 8) = v;
}

// ---------------------------------------------------------------------------
// Spline for one item (math byte-identical to the verified 225us kernel).
// Rf points at this tile's f32 theta overlay; base = row*68 + dl*32.
// ---------------------------------------------------------------------------
__device__ __forceinline__ void spline_eval(const float* __restrict__ Rf, const int base,
                                            const float x2, float& yout, float& ljout)
{
    const float4 v0 = *(const float4*)&Rf[base];
    const float4 v1 = *(const float4*)&Rf[base + 4];
    const float4 v2 = *(const float4*)&Rf[base + 8];
    const float4 v3 = *(const float4*)&Rf[base + 12];
    const float4 v4 = *(const float4*)&Rf[base + 16];

    float tw[10] = {v0.x, v0.y, v0.z, v0.w, v1.x, v1.y, v1.z, v1.w, v2.x, v2.y};
    float m1 = tw[0];
    #pragma unroll
    for (int i = 1; i < 10; ++i) m1 = fmaxf(m1, tw[i]);
    float se = 0.f;
    #pragma unroll
    for (int i = 0; i < 10; ++i) { tw[i] = fexp2((tw[i] - m1) * LOG2E); se += tw[i]; }
    const float inv198 = 1.98f * frcp(se);   // 2*(1-PMIN*K)/sum

    int cnt = 0;
    {
        float run = -1.f;
        cnt += (run < x2) ? 1 : 0;
        #pragma unroll
        for (int i = 0; i < 10; ++i) {
            run = run + fmaf(tw[i], inv198, 0.002f);
            cnt += (run < x2) ? 1 : 0;
        }
    }
    const int bidx = cnt - 1;
    const bool inb = (bidx >= 0) && (bidx < 10);
    const int ci = bidx < 0 ? 0 : (bidx > 9 ? 9 : bidx);

    float xlo = -1.f, xhi = 0.f, rx;
    {
        float run = -1.f;
        #pragma unroll
        for (int i = 0; i < 10; ++i) {
            const bool pick = (i == ci);
            xlo = pick ? run : xlo;
            run = run + fmaf(tw[i], inv198, 0.002f);
            xhi = pick ? run : xhi;
        }
        rx = run;
    }

    float hh[10] = {v2.z, v2.w, v3.x, v3.y, v3.z, v3.w, v4.x, v4.y, v4.z, v4.w};
    float hm = hh[0];
    #pragma unroll
    for (int i = 1; i < 10; ++i) hm = fmaxf(hm, hh[i]);
    float seh = 0.f;
    #pragma unroll
    for (int i = 0; i < 10; ++i) { hh[i] = fexp2((hh[i] - hm) * LOG2E); seh += hh[i]; }
    const float invh = 1.98f * frcp(seh);
    float ylo = -1.f, yhi = 0.f, ry;
    {
        float run = -1.f;
        #pragma unroll
        for (int i = 0; i < 10; ++i) {
            const bool pick = (i == ci);
            ylo = pick ? run : ylo;
            run = run + fmaf(hh[i], invh, 0.002f);
            yhi = pick ? run : yhi;
        }
        ry = run;
    }

    const float xw = xhi - xlo, yw = yhi - ylo;

    const float u1 = Rf[base + 20 + ci];
    const float u2 = Rf[base + 21 + ci];
    const float t1 = u1 * LOG2E;
    const float t2s = u2 * LOG2E;
    const float dd1 = PMIN_F + 0.999f * ((t1  > 15.f) ? t1  : flog2(1.f + fexp2(t1)));
    const float dd2 = PMIN_F + 0.999f * ((t2s > 15.f) ? t2s : flog2(1.f + fexp2(t2s)));

    const float xs  = inb ? x2 : (xlo + 0.5f * xw);
    const float rxw = frcp(xw);
    const float s   = yw * rxw;
    const float eta = (xs - xlo) * rxw;
    const float rev = 1.f - eta;
    const float er  = eta * rev;
    const float dn  = s + (dd1 + dd2 - 2.f * s) * er;
    const float yrq = ylo + yw * (s * eta * eta + dd1 * er) * frcp(dn);
    const float jn  = s * s * (dd2 * eta * eta + 2.f * s * er + dd1 * rev * rev);
    const float ljx = LN2 * (flog2(jn) - 2.f * flog2(dn));
    const float ylin = (ry + 1.f) * frcp(rx + 1.f) * (x2 + 1.f) - 1.f;

    yout  = inb ? yrq : ylin;
    ljout = inb ? ljx : 0.f;
}

// ---------------------------------------------------------------------------
// Main: one wave = 32 rows (2 tiles) — the verified 225us structure — with
// ONE change: weight b-fragments are loaded in explicit register BATCHES
// hoisted ahead of their MFMA chains instead of one-at-a-time just-in-time.
// Round-1 post-mortem: per-wave-latency-bound; ~104 weight loads/layer were
// effectively serialized (~300cy each = ~35K cy exposed/layer vs ~3.5K cy of
// compute). Batching (mm1: 8, mm2: 2x16, mm3: 16/quarter) cuts that to ~6
// batch-latencies; mm3's next-quarter batch is software-pipelined under the
// long spline VALU section.
// Layouts, strides (h f16 132 / theta f32 68), barriers and spline math are
// byte-identical to the verified kernel. LDS 10752 B. Reg peak ~150 < 170
// cap of __launch_bounds__(64,3).
// ---------------------------------------------------------------------------
__global__ __launch_bounds__(64, 3) void flow_mfma(
    const float* __restrict__ x_in,
    const float* __restrict__ c_in,
    const float* __restrict__ bhs,
    const float* __restrict__ bos,
    const int*   __restrict__ perms,
    const _Float16* __restrict__ wsW,
    float* __restrict__ out)
{
    __shared__ __align__(16) float    xls[2][256];   // [tile][16 rows][16]
    __shared__ __align__(16) _Float16 R[2][2176];    // h(f16,132) / theta(f32,68)

    const int lane = threadIdx.x;
    const int q    = lane >> 4;
    const int m    = lane & 15;
    const long long row0 = (long long)blockIdx.x * 32;

    {
        const float4* xp = (const float4*)(x_in + row0 * 16);
        *(float4*)&xls[0][lane * 4] = xp[lane];
        *(float4*)&xls[1][lane * 4] = xp[lane + 64];
    }

    // layer-invariant part of the mm1 A-fragment (c data / bias-one)
    half8 a1c[2];
    #pragma unroll
    for (int t2 = 0; t2 < 2; ++t2) {
        #pragma unroll
        for (int j = 0; j < 8; ++j) a1c[t2][j] = (_Float16)0.f;
        if (q == 1) {
            const float4* cp = (const float4*)(c_in + (row0 + t2 * 16 + m) * 8);
            const float4 c0 = cp[0], c1 = cp[1];
            a1c[t2][0] = (_Float16)c0.x; a1c[t2][1] = (_Float16)c0.y;
            a1c[t2][2] = (_Float16)c0.z; a1c[t2][3] = (_Float16)c0.w;
            a1c[t2][4] = (_Float16)c1.x; a1c[t2][5] = (_Float16)c1.y;
            a1c[t2][6] = (_Float16)c1.z; a1c[t2][7] = (_Float16)c1.w;
        } else if (q == 2) {
            a1c[t2][0] = (_Float16)1.f;   // k=16 -> bias row
        }
    }

    // spline item mapping (fixed per lane): tile, row, d-parity
    const int sp_t2  = lane >> 5;
    const int sp_row = (lane & 31) >> 1;
    const int sp_dl  = lane & 1;

    float ljacc = 0.f;

    for (int l = 0; l < 4; ++l) {
        const _Float16* wsl = wsW + (size_t)l * 104 * 512;
        const float* bh = bhs + l * 128;
        const float* bo = bos + l * 248;

        // ---- batched prefetch: all 8 mm1 b-fragments up front -------------
        half8 bf1[8];
        #pragma unroll
        for (int i = 0; i < 8; ++i)
            bf1[i] = *(const half8*)(wsl + i * 512 + lane * 8);

        // ================= mm1: [x1,c,1] @ [W1;b1] -> h1 (f16) =============
        half8 a1[2];
        #pragma unroll
        for (int t2 = 0; t2 < 2; ++t2) {
            a1[t2] = a1c[t2];
            if (q == 0) {
                const float4 lo = *(const float4*)&xls[t2][m * 16];
                const float4 hi = *(const float4*)&xls[t2][m * 16 + 4];
                a1[t2][0] = (_Float16)lo.x; a1[t2][1] = (_Float16)lo.y;
                a1[t2][2] = (_Float16)lo.z; a1[t2][3] = (_Float16)lo.w;
                a1[t2][4] = (_Float16)hi.x; a1[t2][5] = (_Float16)hi.y;
                a1[t2][6] = (_Float16)hi.z; a1[t2][7] = (_Float16)hi.w;
            }
        }
        #pragma unroll
        for (int g = 0; g < 2; ++g) {
            const floatx4 z = {0.f, 0.f, 0.f, 0.f};
            floatx4 acc0[4], acc1[4];
            #pragma unroll
            for (int nt = 0; nt < 4; ++nt) {
                acc0[nt] = __builtin_amdgcn_mfma_f32_16x16x32_f16(a1[0], bf1[g * 4 + nt], z, 0, 0, 0);
                acc1[nt] = __builtin_amdgcn_mfma_f32_16x16x32_f16(a1[1], bf1[g * 4 + nt], z, 0, 0, 0);
            }
            #pragma unroll
            for (int nt = 0; nt < 4; ++nt)
                #pragma unroll
                for (int reg = 0; reg < 4; ++reg) {
                    R[0][(q * 4 + reg) * 132 + (g * 4 + nt) * 16 + m] = (_Float16)fmaxf(acc0[nt][reg], 0.f);
                    R[1][(q * 4 + reg) * 132 + (g * 4 + nt) * 16 + m] = (_Float16)fmaxf(acc1[nt][reg], 0.f);
                }
        }

        // ===== mm2: pull h1 A-frags (in-order LDS, no barrier needed) ======
        half8 a2[2][4];
        #pragma unroll
        for (int t2 = 0; t2 < 2; ++t2)
            #pragma unroll
            for (int ks = 0; ks < 4; ++ks) {
                const half4v lo = *(const half4v*)&R[t2][m * 132 + ks * 32 + q * 8];
                const half4v hi = *(const half4v*)&R[t2][m * 132 + ks * 32 + q * 8 + 4];
                a2[t2][ks] = __builtin_shufflevector(lo, hi, 0, 1, 2, 3, 4, 5, 6, 7);
            }
        #pragma unroll
        for (int g = 0; g < 2; ++g) {
            // batched prefetch: this g-group's 16 b-fragments
            half8 bf2[16];
            #pragma unroll
            for (int i = 0; i < 16; ++i)
                bf2[i] = *(const half8*)(wsl + (8 + g * 16 + i) * 512 + lane * 8);

            floatx4 acc0[4], acc1[4];
            #pragma unroll
            for (int nt = 0; nt < 4; ++nt) {
                const float bb = bh[(g * 4 + nt) * 16 + m];
                acc0[nt][0] = bb; acc0[nt][1] = bb; acc0[nt][2] = bb; acc0[nt][3] = bb;
                acc1[nt] = acc0[nt];
            }
            #pragma unroll
            for (int ks = 0; ks < 4; ++ks)
                #pragma unroll
                for (int nt = 0; nt < 4; ++nt) {
                    acc0[nt] = __builtin_amdgcn_mfma_f32_16x16x32_f16(a2[0][ks], bf2[nt * 4 + ks], acc0[nt], 0, 0, 0);
                    acc1[nt] = __builtin_amdgcn_mfma_f32_16x16x32_f16(a2[1][ks], bf2[nt * 4 + ks], acc1[nt], 0, 0, 0);
                }
            #pragma unroll
            for (int nt = 0; nt < 4; ++nt)
                #pragma unroll
                for (int reg = 0; reg < 4; ++reg) {
                    R[0][(q * 4 + reg) * 132 + (g * 4 + nt) * 16 + m] = (_Float16)fmaxf(acc0[nt][reg], 0.f);
                    R[1][(q * 4 + reg) * 132 + (g * 4 + nt) * 16 + m] = (_Float16)fmaxf(acc1[nt][reg], 0.f);
                }
        }

        // ===== mm3: pull h2 A-frags to regs ===============================
        half8 a3[2][4];
        #pragma unroll
        for (int t2 = 0; t2 < 2; ++t2)
            #pragma unroll
            for (int ks = 0; ks < 4; ++ks) {
                const half4v lo = *(const half4v*)&R[t2][m * 132 + ks * 32 + q * 8];
                const half4v hi = *(const half4v*)&R[t2][m * 132 + ks * 32 + q * 8 + 4];
                a3[t2][ks] = __builtin_shufflevector(lo, hi, 0, 1, 2, 3, 4, 5, 6, 7);
            }
        __syncthreads();   // FENCE: f16 h-reads above vs f32 theta-writes below

        float* Rf0 = (float*)&R[0][0];
        float* Rf1 = (float*)&R[1][0];

        // ---- mm3 quarter pipeline: prefetch quarter 0's 16 b-fragments ----
        half8 bf3[2][16];
        #pragma unroll
        for (int i = 0; i < 16; ++i)
            bf3[0][i] = *(const half8*)(wsl + (40 + i) * 512 + lane * 8);

        #pragma unroll
        for (int qd = 0; qd < 4; ++qd) {
            // ---- mm3 quarter: cols [qd*64, qd*64+64) = d in {qd*2, qd*2+1}
            {
                floatx4 acc0[4], acc1[4];
                #pragma unroll
                for (int j = 0; j < 4; ++j) {
                    const int n = qd * 64 + j * 16 + m;
                    const int cc = n & 31;
                    const float bb = (cc < 31) ? bo[(n >> 5) * 31 + cc] : 0.f;
                    acc0[j][0] = bb; acc0[j][1] = bb; acc0[j][2] = bb; acc0[j][3] = bb;
                    acc1[j] = acc0[j];
                }
                #pragma unroll
                for (int ks = 0; ks < 4; ++ks)
                    #pragma unroll
                    for (int j = 0; j < 4; ++j) {
                        acc0[j] = __builtin_amdgcn_mfma_f32_16x16x32_f16(a3[0][ks], bf3[qd & 1][j * 4 + ks], acc0[j], 0, 0, 0);
                        acc1[j] = __builtin_amdgcn_mfma_f32_16x16x32_f16(a3[1][ks], bf3[qd & 1][j * 4 + ks], acc1[j], 0, 0, 0);
                    }
                // store theta as f32: addr = row*68 + (j>>1)*32 + ((j&1)*16+m)
                #pragma unroll
                for (int j = 0; j < 4; ++j) {
                    const int off = (j >> 1) * 32 + (j & 1) * 16 + m;
                    #pragma unroll
                    for (int reg = 0; reg < 4; ++reg) {
                        Rf0[(q * 4 + reg) * 68 + off] = acc0[j][reg];
                        Rf1[(q * 4 + reg) * 68 + off] = acc1[j][reg];
                    }
                }
            }

            // ---- prefetch next quarter's b-fragments; the spline below
            //      (long serial VALU) covers their L2 latency --------------
            if (qd < 3) {
                #pragma unroll
                for (int i = 0; i < 16; ++i)
                    bf3[(qd + 1) & 1][i] = *(const half8*)(wsl + (40 + (qd + 1) * 16 + i) * 512 + lane * 8);
            }

            // ---- spline quarter: 64 items, 1/lane: (sp_t2, sp_row, d) -----
            {
                const int d    = qd * 2 + sp_dl;
                const int base = sp_row * 68 + sp_dl * 32;
                const float* Rf = sp_t2 ? Rf1 : Rf0;
                const int xi   = sp_row * 16 + 8 + d;

                float yv, lj;
                spline_eval(Rf, base, xls[sp_t2][xi], yv, lj);
                xls[sp_t2][xi] = yv;
                ljacc += lj;
            }
        }

        // ================= permutation (in-order LDS, same-type) ===========
        {
            const int4 pv = ((const int4*)(perms + l * 16))[lane & 3];
            const int mm = lane >> 2;
            const float a0 = xls[0][mm * 16 + pv.x];
            const float a1v = xls[0][mm * 16 + pv.y];
            const float a2v = xls[0][mm * 16 + pv.z];
            const float a3v = xls[0][mm * 16 + pv.w];
            const float b0 = xls[1][mm * 16 + pv.x];
            const float b1v = xls[1][mm * 16 + pv.y];
            const float b2 = xls[1][mm * 16 + pv.z];
            const float b3 = xls[1][mm * 16 + pv.w];
            *(float4*)&xls[0][lane * 4] = make_float4(a0, a1v, a2v, a3v);
            *(float4*)&xls[1][lane * 4] = make_float4(b0, b1v, b2, b3);
        }
        __syncthreads();   // FENCE: f32 theta-reads this layer vs f16 h-writes next
    }

    // ---- outputs: x [B,16] then ljd [B]
    #pragma unroll
    for (int t2 = 0; t2 < 2; ++t2) {
        const float4 vo = *(const float4*)&xls[t2][lane * 4];
        ((float4*)(out + (row0 + t2 * 16) * 16))[lane] = vo;
    }
    {
        const float ljs = ljacc + __shfl_xor(ljacc, 1);
        if ((lane & 1) == 0)
            out[(size_t)B_N * 16 + row0 + sp_t2 * 16 + sp_row] = ljs;
    }
}

extern "C" void kernel_launch(void* const* d_in, const int* in_sizes, int n_in,
                              void* d_out, int out_size, void* d_ws, size_t ws_size,
                              hipStream_t stream) {
    const float* x     = (const float*)d_in[0];
    const float* c     = (const float*)d_in[1];
    const float* W1s   = (const float*)d_in[2];
    const float* b1s   = (const float*)d_in[3];
    const float* Whs   = (const float*)d_in[4];
    const float* bhs   = (const float*)d_in[5];
    const float* Wos   = (const float*)d_in[6];
    const float* bos   = (const float*)d_in[7];
    const int*   perms = (const int*)d_in[8];
    float* out = (float*)d_out;
    _Float16* ws = (_Float16*)d_ws;

    prep_kernel<<<dim3(416), dim3(64), 0, stream>>>(W1s, b1s, Whs, Wos, ws);
    flow_mfma<<<dim3(B_N / 32), dim3(64), 0, stream>>>(
        x, c, bhs, bos, perms, ws, out);
}